// Round 2
// baseline (237.760 us; speedup 1.0000x reference)
//
#include <hip/hip_runtime.h>
#include <math.h>

#define BB 32
#define CC 256
#define NN 1024
#define KSTR 264   // u16 stride for K-tile rows (256 + 8 pad -> 2-way-free b128 reads)
#define PSTR 40
#define THR 8.0f

typedef unsigned short u16;
typedef u16 u16x8 __attribute__((ext_vector_type(8)));
typedef _Float16 h16;
typedef h16 h16x8 __attribute__((ext_vector_type(8)));
typedef h16 h16x4 __attribute__((ext_vector_type(4)));
typedef float f32x4 __attribute__((ext_vector_type(4)));

__device__ __forceinline__ h16x8 ldh8(const u16* p) {
    return __builtin_bit_cast(h16x8, *(const u16x8*)p);
}
__device__ __forceinline__ f32x4 mfma16(h16x8 a, h16x8 b, f32x4 c) {
    return __builtin_amdgcn_mfma_f32_16x16x32_f16(a, b, c, 0, 0, 0);
}

// ---------------------------------------------------------------------------
// Kernel 1: transpose x[b][c][p] (fp32) -> qf [b][p][c] (fp16)
// ---------------------------------------------------------------------------
__global__ __launch_bounds__(256) void k_split(const float* __restrict__ x,
                                               u16* __restrict__ qf) {
    __shared__ float lds[64][65];
    int bid = blockIdx.x;
    int b = bid >> 6, ct = (bid >> 4) & 3, pt = bid & 15;
    int t = threadIdx.x;
    int c0 = ct * 64, p0 = pt * 64;
    const float* xb = x + ((size_t)b * CC + c0) * NN + p0;
#pragma unroll
    for (int it = 0; it < 4; ++it) {
        int cl = (t >> 4) + it * 16;
        int pl = (t & 15) * 4;
        float4 v = *(const float4*)(xb + (size_t)cl * NN + pl);
        lds[pl + 0][cl] = v.x;
        lds[pl + 1][cl] = v.y;
        lds[pl + 2][cl] = v.z;
        lds[pl + 3][cl] = v.w;
    }
    __syncthreads();
    u16* qb = qf + ((size_t)b * NN + p0) * CC + c0;
#pragma unroll
    for (int it = 0; it < 2; ++it) {
        int pl = (t >> 3) + it * 32;
        int cl = (t & 7) * 8;
        u16x8 hv;
#pragma unroll
        for (int e = 0; e < 8; ++e) hv[e] = __builtin_bit_cast(u16, (h16)lds[pl][cl + e]);
        *(u16x8*)(qb + (size_t)pl * CC + cl) = hv;
    }
}

// ---------------------------------------------------------------------------
// Kernel 2: V[b][o][p] = sum_c W[o][c] * X[b][c][p] + bias[o]  (fp16 out)
// ---------------------------------------------------------------------------
__global__ __launch_bounds__(256, 2) void k_vgemm(const u16* __restrict__ qf,
                                                  const float* __restrict__ w,
                                                  const float* __restrict__ bias,
                                                  u16* __restrict__ vbf) {
    int bid = blockIdx.x;
    int b = bid >> 4, pt = bid & 15;
    int t = threadIdx.x;
    int wave = t >> 6, lane = t & 63;
    int l15 = lane & 15, l4 = lane >> 4;
    int p0 = pt * 64, o0 = wave * 64;
    f32x4 acc[4][4];
#pragma unroll
    for (int m = 0; m < 4; ++m)
#pragma unroll
        for (int n = 0; n < 4; ++n) acc[m][n] = (f32x4){0.f, 0.f, 0.f, 0.f};
#pragma unroll
    for (int ks = 0; ks < 8; ++ks) {
        int kk = ks * 32 + 8 * l4;
        h16x8 afr[4], bfr[4];
#pragma unroll
        for (int m = 0; m < 4; ++m) {
            const float* wp = w + (size_t)(o0 + m * 16 + l15) * CC + kk;
            float4 w0 = *(const float4*)wp;
            float4 w1 = *(const float4*)(wp + 4);
            h16x8 tv;
            tv[0] = (h16)w0.x; tv[1] = (h16)w0.y; tv[2] = (h16)w0.z; tv[3] = (h16)w0.w;
            tv[4] = (h16)w1.x; tv[5] = (h16)w1.y; tv[6] = (h16)w1.z; tv[7] = (h16)w1.w;
            afr[m] = tv;
        }
#pragma unroll
        for (int n = 0; n < 4; ++n)
            bfr[n] = ldh8(qf + ((size_t)b * NN + p0 + n * 16 + l15) * CC + kk);
#pragma unroll
        for (int m = 0; m < 4; ++m)
#pragma unroll
            for (int n = 0; n < 4; ++n) acc[m][n] = mfma16(afr[m], bfr[n], acc[m][n]);
    }
#pragma unroll
    for (int m = 0; m < 4; ++m) {
#pragma unroll
        for (int r = 0; r < 4; ++r) {
            int o = o0 + m * 16 + 4 * l4 + r;
            float bv = bias[o];
            u16* vp = vbf + ((size_t)b * CC + o) * NN + p0 + l15;
#pragma unroll
            for (int n = 0; n < 4; ++n)
                vp[n * 16] = __builtin_bit_cast(u16, (h16)(acc[m][n][r] + bv));
        }
    }
}

// ---------------------------------------------------------------------------
// Kernel 3: flash attention (swapped-QK, lane-local softmax, defer-max,
// K double-buffered in LDS w/ reg-prefetch, V fragment-direct from global)
// + fused interleaved reshape + 2x2 maxpool epilogue.
// Block = (batch, 64 query rows), 4 waves x 16 rows.
// ---------------------------------------------------------------------------
#define SMEM_BYTES 39424
__global__ __launch_bounds__(256, 2) void k_attn(const u16* __restrict__ qf,
                                                 const u16* __restrict__ vbf,
                                                 float* __restrict__ out) {
    __shared__ __align__(16) char smem[SMEM_BYTES];
    u16* Kt = (u16*)smem;                // 2 x [32][KSTR] fp16 (33792 B)
    u16* Pt = (u16*)(smem + 33792);      // [4 waves][16][PSTR] (5120 B)
    float* Sc = (float*)(smem + 38912);  // [4 waves][16] f32 broadcast scratch

    int bid = blockIdx.x;
    int xcd = bid & 7, s0 = bid >> 3;
    int b = xcd * 4 + (s0 >> 4);
    int iblk = s0 & 15;
    int i0 = iblk * 64;
    int t = threadIdx.x;
    int wave = t >> 6, lane = t & 63;
    int l15 = lane & 15, l4 = lane >> 4;
    int iw = i0 + wave * 16;

    const u16* qb = qf + (size_t)b * NN * CC;
    const u16* vbb = vbf + (size_t)b * CC * NN;

    // Q fragments in registers: lane holds query row iw+l15, k = ks*32+8*l4..
    h16x8 qfr[8];
#pragma unroll
    for (int ks = 0; ks < 8; ++ks)
        qfr[ks] = ldh8(qb + (size_t)(iw + l15) * CC + ks * 32 + 8 * l4);

    f32x4 oacc[16];
#pragma unroll
    for (int i = 0; i < 16; ++i) oacc[i] = (f32x4){0.f, 0.f, 0.f, 0.f};
    float m = -INFINITY, l = 0.f;

    // stage K tile 0 into buffer 0
    {
        u16x8 kp[4];
#pragma unroll
        for (int p = 0; p < 4; ++p) {
            int sidx = t + p * 256;
            kp[p] = *(const u16x8*)(qb + (size_t)(sidx >> 5) * CC + (sidx & 31) * 8);
        }
#pragma unroll
        for (int p = 0; p < 4; ++p) {
            int sidx = t + p * 256;
            *(u16x8*)&Kt[(sidx >> 5) * KSTR + (sidx & 31) * 8] = kp[p];
        }
    }
    __syncthreads();

    u16* Pw = Pt + wave * 16 * PSTR;
    float* Scw = Sc + wave * 16;

    for (int jt = 0; jt < 32; ++jt) {
        int cur = jt & 1;
        int j0 = jt * 32;
        const u16* Kc = Kt + cur * (32 * KSTR) + l15 * KSTR + 8 * l4;

        // V fragments for this tile, direct from global (L1/L2-resident)
        u16x8 vf[16];
#pragma unroll
        for (int of = 0; of < 16; ++of)
            vf[of] = *(const u16x8*)(vbb + (size_t)(of * 16 + l15) * NN + j0 + 8 * l4);

        // K prefetch for next tile (into regs; written to LDS after compute)
        u16x8 kp[4];
        if (jt < 31) {
#pragma unroll
            for (int p = 0; p < 4; ++p) {
                int sidx = t + p * 256;
                kp[p] = *(const u16x8*)(qb + (size_t)(j0 + 32 + (sidx >> 5)) * CC +
                                        (sidx & 31) * 8);
            }
        }

        // QK^T swapped: A = K rows (j), B = Q rows (i).
        // s0v[r] = S[j=4*l4+r][i=l15], s1v[r] = S[j=16+4*l4+r][i=l15]
        f32x4 s0v = (f32x4){0.f, 0.f, 0.f, 0.f};
        f32x4 s1v = (f32x4){0.f, 0.f, 0.f, 0.f};
#pragma unroll
        for (int ks = 0; ks < 8; ++ks) {
            h16x8 a0 = ldh8(Kc + ks * 32);
            h16x8 a1 = ldh8(Kc + 16 * KSTR + ks * 32);
            s0v = mfma16(a0, qfr[ks], s0v);
            s1v = mfma16(a1, qfr[ks], s1v);
        }

        // lane-local softmax for query i = l15 (8 scores per lane)
        float mx = fmaxf(fmaxf(fmaxf(s0v[0], s0v[1]), fmaxf(s0v[2], s0v[3])),
                         fmaxf(fmaxf(s1v[0], s1v[1]), fmaxf(s1v[2], s1v[3])));
        mx = fmaxf(mx, __shfl_xor(mx, 16));
        mx = fmaxf(mx, __shfl_xor(mx, 32));
        if (__any(mx > m + THR)) {  // defer-max: rescale only on real growth
            float mnew = fmaxf(m, mx);
            float sc = __expf(m - mnew);
            m = mnew;
            l *= sc;
            Scw[l15] = sc;  // broadcast i-indexed scale to row-layout lanes
            f32x4 s4 = *(f32x4*)&Scw[4 * l4];
#pragma unroll
            for (int of = 0; of < 16; ++of)
#pragma unroll
                for (int r = 0; r < 4; ++r) oacc[of][r] *= s4[r];
        }
        float p0 = __expf(s0v[0] - m), p1 = __expf(s0v[1] - m);
        float p2 = __expf(s0v[2] - m), p3 = __expf(s0v[3] - m);
        float p4 = __expf(s1v[0] - m), p5 = __expf(s1v[1] - m);
        float p6 = __expf(s1v[2] - m), p7 = __expf(s1v[3] - m);
        float rs = ((p0 + p1) + (p2 + p3)) + ((p4 + p5) + (p6 + p7));
        rs += __shfl_xor(rs, 16);
        rs += __shfl_xor(rs, 32);
        l += rs;

        // P -> fp16 -> per-wave LDS transpose -> A-frag
        h16x4 pk0 = {(h16)p0, (h16)p1, (h16)p2, (h16)p3};  // j = 4*l4+0..3
        h16x4 pk1 = {(h16)p4, (h16)p5, (h16)p6, (h16)p7};  // j = 16+4*l4+0..3
        *(h16x4*)(Pw + l15 * PSTR + 4 * l4) = pk0;
        *(h16x4*)(Pw + l15 * PSTR + 16 + 4 * l4) = pk1;
        h16x8 pa = ldh8(Pw + l15 * PSTR + 8 * l4);

        // PV: O[i][o] += P[i][j] V[j][o]
#pragma unroll
        for (int of = 0; of < 16; ++of)
            oacc[of] = mfma16(pa, __builtin_bit_cast(h16x8, vf[of]), oacc[of]);

        // write prefetched K tile to the other buffer; one barrier per jt
        if (jt < 31) {
#pragma unroll
            for (int p = 0; p < 4; ++p) {
                int sidx = t + p * 256;
                *(u16x8*)&Kt[(cur ^ 1) * (32 * KSTR) + (sidx >> 5) * KSTR +
                             (sidx & 31) * 8] = kp[p];
            }
            __syncthreads();
        }
    }

    // normalize: broadcast 1/l from i=l15 layout to row(4*l4+r) layout
    {
        float inv = 1.0f / l;
        Scw[l15] = inv;
        f32x4 inv4 = *(f32x4*)&Scw[4 * l4];
#pragma unroll
        for (int of = 0; of < 16; ++of)
#pragma unroll
            for (int r = 0; r < 4; ++r) oacc[of][r] *= inv4[r];
    }

    // Epilogue: 2-pass through LDS, interleaved reshape + 2x2 maxpool.
    // oacc layout: row i = 4*l4 + r (within wave's 16), col o = of*16 + l15.
    float* Old = (float*)smem;  // [32][260]
#pragma unroll
    for (int half = 0; half < 2; ++half) {
        __syncthreads();
        if ((wave >> 1) == half) {
            int wrow = (wave & 1) * 16;
#pragma unroll
            for (int of = 0; of < 16; ++of)
#pragma unroll
                for (int r = 0; r < 4; ++r)
                    Old[(wrow + 4 * l4 + r) * 260 + of * 16 + l15] = oacc[of][r];
        }
        __syncthreads();
#pragma unroll
        for (int it = 0; it < 8; ++it) {
            int q = it * 16 + (t >> 4);
            int ill = q >> 2, pl = q & 3, pw = t & 15;
            const float* row = &Old[ill * 260];
            int ob = pl * 64 + pw * 2;
            float mx = fmaxf(fmaxf(row[ob], row[ob + 1]),
                             fmaxf(row[ob + 32], row[ob + 33]));
            int i = i0 + half * 32 + ill;
            out[(((size_t)b * CC + (i >> 2)) * 16 + (i & 3) * 4 + pl) * 16 + pw] = mx;
        }
    }
}

// ---------------------------------------------------------------------------
extern "C" void kernel_launch(void* const* d_in, const int* in_sizes, int n_in,
                              void* d_out, int out_size, void* d_ws, size_t ws_size,
                              hipStream_t stream) {
    const float* x = (const float*)d_in[0];
    const float* w = (const float*)d_in[1];
    const float* bias = (const float*)d_in[2];
    float* out = (float*)d_out;
    u16* qf = (u16*)d_ws;                   // [32][1024][256] fp16
    u16* vbf = qf + (size_t)BB * NN * CC;   // [32][256][1024] fp16
    k_split<<<2048, 256, 0, stream>>>(x, qf);
    k_vgemm<<<512, 256, 0, stream>>>(qf, w, bias, vbf);
    k_attn<<<512, 256, 0, stream>>>(qf, vbf, out);
}

// Round 3
// 147.620 us; speedup vs baseline: 1.6106x; 1.6106x over previous
//
#include <hip/hip_runtime.h>
#include <math.h>

#define BB 32
#define CC 256
#define NN 1024
#define KSTR 264   // u16 stride for K-tile rows (256 + 8 pad -> 2-way-free b128 reads)
#define PSTR 40
#define THR 8.0f

typedef unsigned short u16;
typedef u16 u16x8 __attribute__((ext_vector_type(8)));
typedef _Float16 h16;
typedef h16 h16x8 __attribute__((ext_vector_type(8)));
typedef h16 h16x4 __attribute__((ext_vector_type(4)));
typedef float f32x4 __attribute__((ext_vector_type(4)));

__device__ __forceinline__ h16x8 ldh8(const u16* p) {
    return __builtin_bit_cast(h16x8, *(const u16x8*)p);
}
__device__ __forceinline__ f32x4 mfma16(h16x8 a, h16x8 b, f32x4 c) {
    return __builtin_amdgcn_mfma_f32_16x16x32_f16(a, b, c, 0, 0, 0);
}

// ---------------------------------------------------------------------------
// Kernel 0: W f32 [256][256] -> fragment-major fp16 Whf.
// Slot s = (ot*8 + ks)*64 + lane; element e: W[ot*16 + (l&15)][ks*32 + 8*(l>>4) + e]
// ---------------------------------------------------------------------------
__global__ __launch_bounds__(256) void k_wprep(const float* __restrict__ w,
                                               u16* __restrict__ whf) {
    int s = blockIdx.x * 256 + threadIdx.x;  // 8192 slots
    int ot = s >> 9, ks = (s >> 6) & 7, l = s & 63;
    const float* src = w + (size_t)(ot * 16 + (l & 15)) * CC + ks * 32 + 8 * (l >> 4);
    float4 a = *(const float4*)src;
    float4 c = *(const float4*)(src + 4);
    u16x8 o;
    o[0] = __builtin_bit_cast(u16, (h16)a.x); o[1] = __builtin_bit_cast(u16, (h16)a.y);
    o[2] = __builtin_bit_cast(u16, (h16)a.z); o[3] = __builtin_bit_cast(u16, (h16)a.w);
    o[4] = __builtin_bit_cast(u16, (h16)c.x); o[5] = __builtin_bit_cast(u16, (h16)c.y);
    o[6] = __builtin_bit_cast(u16, (h16)c.z); o[7] = __builtin_bit_cast(u16, (h16)c.w);
    *(u16x8*)(whf + (size_t)s * 8) = o;
}

// ---------------------------------------------------------------------------
// Kernel 1: transpose x[b][c][p] (fp32) -> qf [b][p][c] (fp16)
// ---------------------------------------------------------------------------
__global__ __launch_bounds__(256) void k_split(const float* __restrict__ x,
                                               u16* __restrict__ qf) {
    __shared__ float lds[64][65];
    int bid = blockIdx.x;
    int b = bid >> 6, ct = (bid >> 4) & 3, pt = bid & 15;
    int t = threadIdx.x;
    int c0 = ct * 64, p0 = pt * 64;
    const float* xb = x + ((size_t)b * CC + c0) * NN + p0;
#pragma unroll
    for (int it = 0; it < 4; ++it) {
        int cl = (t >> 4) + it * 16;
        int pl = (t & 15) * 4;
        float4 v = *(const float4*)(xb + (size_t)cl * NN + pl);
        lds[pl + 0][cl] = v.x;
        lds[pl + 1][cl] = v.y;
        lds[pl + 2][cl] = v.z;
        lds[pl + 3][cl] = v.w;
    }
    __syncthreads();
    u16* qb = qf + ((size_t)b * NN + p0) * CC + c0;
#pragma unroll
    for (int it = 0; it < 2; ++it) {
        int pl = (t >> 3) + it * 32;
        int cl = (t & 7) * 8;
        u16x8 hv;
#pragma unroll
        for (int e = 0; e < 8; ++e) hv[e] = __builtin_bit_cast(u16, (h16)lds[pl][cl + e]);
        *(u16x8*)(qb + (size_t)pl * CC + cl) = hv;
    }
}

// ---------------------------------------------------------------------------
// Kernel 2: V = W@X + b, output in PV-fragment-major layout Vf:
// Vf[((b*32 + jt)*16 + of)*512 + l*8 + e] = V[b][o=of*16+(l&15)][j=jt*32+8*(l>>4)+e]
// Block: (b, p-tile 64), 4 waves each own 64 o-channels.
// B-frags from LDS-staged X-tile (coalesced), A-frags from Whf (coalesced).
// ---------------------------------------------------------------------------
__global__ __launch_bounds__(256, 2) void k_vgemm(const u16* __restrict__ qf,
                                                  const u16* __restrict__ whf,
                                                  const float* __restrict__ bias,
                                                  u16* __restrict__ vf) {
    __shared__ __align__(16) u16 smem[18432];  // Xs [64][264] (16896) / Vs 4x[64][72]
    int bid = blockIdx.x;
    int b = bid >> 4, pt = bid & 15;
    int t = threadIdx.x;
    int wave = t >> 6, lane = t & 63;
    int l15 = lane & 15, l4 = lane >> 4;
    int p0 = pt * 64, o0 = wave * 64;

    // stage X-tile [64 p][256 c] into Xs (coalesced row reads)
#pragma unroll
    for (int it = 0; it < 8; ++it) {
        int sidx = t + it * 256;
        int row = sidx >> 5, ch = (sidx & 31) * 8;
        *(u16x8*)&smem[row * KSTR + ch] =
            *(const u16x8*)(qf + ((size_t)b * NN + p0 + row) * CC + ch);
    }
    __syncthreads();

    f32x4 acc[4][4];
#pragma unroll
    for (int m = 0; m < 4; ++m)
#pragma unroll
        for (int n = 0; n < 4; ++n) acc[m][n] = (f32x4){0.f, 0.f, 0.f, 0.f};
#pragma unroll
    for (int ks = 0; ks < 8; ++ks) {
        h16x8 afr[4], bfr[4];
#pragma unroll
        for (int m = 0; m < 4; ++m)
            afr[m] = ldh8(whf + (size_t)(((wave * 4 + m) * 8 + ks) * 64 + lane) * 8);
#pragma unroll
        for (int n = 0; n < 4; ++n)
            bfr[n] = ldh8(&smem[(n * 16 + l15) * KSTR + ks * 32 + 8 * l4]);
#pragma unroll
        for (int m = 0; m < 4; ++m)
#pragma unroll
            for (int n = 0; n < 4; ++n) acc[m][n] = mfma16(afr[m], bfr[n], acc[m][n]);
    }
    __syncthreads();  // all waves done reading Xs before overwrite

    // per-wave transpose through LDS: Vs[o_local][j_local], stride 72 (+8 pad)
    u16* Vs = smem + wave * 4608;
#pragma unroll
    for (int m = 0; m < 4; ++m) {
#pragma unroll
        for (int r = 0; r < 4; ++r) {
            int ol = m * 16 + 4 * l4 + r;
            float bv = bias[o0 + ol];
#pragma unroll
            for (int n = 0; n < 4; ++n)
                Vs[ol * 72 + n * 16 + l15] =
                    __builtin_bit_cast(u16, (h16)(acc[m][n][r] + bv));
        }
    }
    // read out in fragment order (same wave; in-order LDS) and store coalesced
#pragma unroll
    for (int m = 0; m < 4; ++m) {
#pragma unroll
        for (int jtl = 0; jtl < 2; ++jtl) {
            u16x8 v = *(u16x8*)&Vs[(m * 16 + l15) * 72 + jtl * 32 + 8 * l4];
            size_t idx = (((size_t)b * 32 + pt * 2 + jtl) * 16 + wave * 4 + m) * 512 +
                         lane * 8;
            *(u16x8*)(vf + idx) = v;
        }
    }
}

// ---------------------------------------------------------------------------
// Kernel 3: flash attention (swapped-QK, lane-local softmax, defer-max,
// K double-buffered in LDS w/ reg-prefetch, V coalesced from fragment-major Vf)
// + fused interleaved reshape + 2x2 maxpool epilogue.
// Block = (batch, 64 query rows), 4 waves x 16 rows.
// ---------------------------------------------------------------------------
#define SMEM_BYTES 39424
__global__ __launch_bounds__(256, 2) void k_attn(const u16* __restrict__ qf,
                                                 const u16* __restrict__ vf,
                                                 float* __restrict__ out) {
    __shared__ __align__(16) char smem[SMEM_BYTES];
    u16* Kt = (u16*)smem;                // 2 x [32][KSTR] fp16 (33792 B)
    u16* Pt = (u16*)(smem + 33792);      // [4 waves][16][PSTR] (5120 B)
    float* Sc = (float*)(smem + 38912);  // [4 waves][16] f32 broadcast scratch

    int bid = blockIdx.x;
    int xcd = bid & 7, s0 = bid >> 3;
    int b = xcd * 4 + (s0 >> 4);
    int iblk = s0 & 15;
    int i0 = iblk * 64;
    int t = threadIdx.x;
    int wave = t >> 6, lane = t & 63;
    int l15 = lane & 15, l4 = lane >> 4;
    int iw = i0 + wave * 16;

    const u16* qb = qf + (size_t)b * NN * CC;
    const u16* vfb = vf + (size_t)b * (32 * 16 * 512);

    // Q fragments in registers: lane holds query row iw+l15, k = ks*32+8*l4..
    h16x8 qfr[8];
#pragma unroll
    for (int ks = 0; ks < 8; ++ks)
        qfr[ks] = ldh8(qb + (size_t)(iw + l15) * CC + ks * 32 + 8 * l4);

    f32x4 oacc[16];
#pragma unroll
    for (int i = 0; i < 16; ++i) oacc[i] = (f32x4){0.f, 0.f, 0.f, 0.f};
    float m = -INFINITY, l = 0.f;

    // stage K tile 0 into buffer 0
    {
        u16x8 kp[4];
#pragma unroll
        for (int p = 0; p < 4; ++p) {
            int sidx = t + p * 256;
            kp[p] = *(const u16x8*)(qb + (size_t)(sidx >> 5) * CC + (sidx & 31) * 8);
        }
#pragma unroll
        for (int p = 0; p < 4; ++p) {
            int sidx = t + p * 256;
            *(u16x8*)&Kt[(sidx >> 5) * KSTR + (sidx & 31) * 8] = kp[p];
        }
    }
    __syncthreads();

    u16* Pw = Pt + wave * 16 * PSTR;
    float* Scw = Sc + wave * 16;

    for (int jt = 0; jt < 32; ++jt) {
        int cur = jt & 1;
        int j0 = jt * 32;
        const u16* Kc = Kt + cur * (32 * KSTR) + l15 * KSTR + 8 * l4;

        // V fragments for this tile: COALESCED b128 from fragment-major Vf
        u16x8 vfr[16];
#pragma unroll
        for (int of = 0; of < 16; ++of)
            vfr[of] = *(const u16x8*)(vfb + ((size_t)(jt * 16 + of) * 512 + lane * 8));

        // K prefetch for next tile (into regs; written to LDS after compute)
        u16x8 kp[4];
        if (jt < 31) {
#pragma unroll
            for (int p = 0; p < 4; ++p) {
                int sidx = t + p * 256;
                kp[p] = *(const u16x8*)(qb + (size_t)(j0 + 32 + (sidx >> 5)) * CC +
                                        (sidx & 31) * 8);
            }
        }

        // QK^T swapped: A = K rows (j), B = Q rows (i).
        // s0v[r] = S[j=4*l4+r][i=l15], s1v[r] = S[j=16+4*l4+r][i=l15]
        f32x4 s0v = (f32x4){0.f, 0.f, 0.f, 0.f};
        f32x4 s1v = (f32x4){0.f, 0.f, 0.f, 0.f};
#pragma unroll
        for (int ks = 0; ks < 8; ++ks) {
            h16x8 a0 = ldh8(Kc + ks * 32);
            h16x8 a1 = ldh8(Kc + 16 * KSTR + ks * 32);
            s0v = mfma16(a0, qfr[ks], s0v);
            s1v = mfma16(a1, qfr[ks], s1v);
        }

        // lane-local softmax for query i = l15 (8 scores per lane)
        float mx = fmaxf(fmaxf(fmaxf(s0v[0], s0v[1]), fmaxf(s0v[2], s0v[3])),
                         fmaxf(fmaxf(s1v[0], s1v[1]), fmaxf(s1v[2], s1v[3])));
        mx = fmaxf(mx, __shfl_xor(mx, 16));
        mx = fmaxf(mx, __shfl_xor(mx, 32));
        if (__any(mx > m + THR)) {  // defer-max: rescale only on real growth
            float mnew = fmaxf(m, mx);
            float sc = __expf(m - mnew);
            m = mnew;
            l *= sc;
            Scw[l15] = sc;  // broadcast i-indexed scale to row-layout lanes
            f32x4 s4 = *(f32x4*)&Scw[4 * l4];
#pragma unroll
            for (int of = 0; of < 16; ++of)
#pragma unroll
                for (int r = 0; r < 4; ++r) oacc[of][r] *= s4[r];
        }
        float p0 = __expf(s0v[0] - m), p1 = __expf(s0v[1] - m);
        float p2 = __expf(s0v[2] - m), p3 = __expf(s0v[3] - m);
        float p4 = __expf(s1v[0] - m), p5 = __expf(s1v[1] - m);
        float p6 = __expf(s1v[2] - m), p7 = __expf(s1v[3] - m);
        float rs = ((p0 + p1) + (p2 + p3)) + ((p4 + p5) + (p6 + p7));
        rs += __shfl_xor(rs, 16);
        rs += __shfl_xor(rs, 32);
        l += rs;

        // P -> fp16 -> per-wave LDS transpose -> A-frag
        h16x4 pk0 = {(h16)p0, (h16)p1, (h16)p2, (h16)p3};  // j = 4*l4+0..3
        h16x4 pk1 = {(h16)p4, (h16)p5, (h16)p6, (h16)p7};  // j = 16+4*l4+0..3
        *(h16x4*)(Pw + l15 * PSTR + 4 * l4) = pk0;
        *(h16x4*)(Pw + l15 * PSTR + 16 + 4 * l4) = pk1;
        h16x8 pa = ldh8(Pw + l15 * PSTR + 8 * l4);

        // PV: O[i][o] += P[i][j] V[j][o]
#pragma unroll
        for (int of = 0; of < 16; ++of)
            oacc[of] = mfma16(pa, __builtin_bit_cast(h16x8, vfr[of]), oacc[of]);

        // write prefetched K tile to the other buffer; one barrier per jt
        if (jt < 31) {
#pragma unroll
            for (int p = 0; p < 4; ++p) {
                int sidx = t + p * 256;
                *(u16x8*)&Kt[(cur ^ 1) * (32 * KSTR) + (sidx >> 5) * KSTR +
                             (sidx & 31) * 8] = kp[p];
            }
            __syncthreads();
        }
    }

    // normalize: broadcast 1/l from i=l15 layout to row(4*l4+r) layout
    {
        float inv = 1.0f / l;
        Scw[l15] = inv;
        f32x4 inv4 = *(f32x4*)&Scw[4 * l4];
#pragma unroll
        for (int of = 0; of < 16; ++of)
#pragma unroll
            for (int r = 0; r < 4; ++r) oacc[of][r] *= inv4[r];
    }

    // Epilogue: 2-pass through LDS, interleaved reshape + 2x2 maxpool.
    // oacc layout: row i = 4*l4 + r (within wave's 16), col o = of*16 + l15.
    float* Old = (float*)smem;  // [32][260]
#pragma unroll
    for (int half = 0; half < 2; ++half) {
        __syncthreads();
        if ((wave >> 1) == half) {
            int wrow = (wave & 1) * 16;
#pragma unroll
            for (int of = 0; of < 16; ++of)
#pragma unroll
                for (int r = 0; r < 4; ++r)
                    Old[(wrow + 4 * l4 + r) * 260 + of * 16 + l15] = oacc[of][r];
        }
        __syncthreads();
#pragma unroll
        for (int it = 0; it < 8; ++it) {
            int q = it * 16 + (t >> 4);
            int ill = q >> 2, pl = q & 3, pw = t & 15;
            const float* row = &Old[ill * 260];
            int ob = pl * 64 + pw * 2;
            float mx = fmaxf(fmaxf(row[ob], row[ob + 1]),
                             fmaxf(row[ob + 32], row[ob + 33]));
            int i = i0 + half * 32 + ill;
            out[(((size_t)b * CC + (i >> 2)) * 16 + (i & 3) * 4 + pl) * 16 + pw] = mx;
        }
    }
}

// ---------------------------------------------------------------------------
extern "C" void kernel_launch(void* const* d_in, const int* in_sizes, int n_in,
                              void* d_out, int out_size, void* d_ws, size_t ws_size,
                              hipStream_t stream) {
    const float* x = (const float*)d_in[0];
    const float* w = (const float*)d_in[1];
    const float* bias = (const float*)d_in[2];
    float* out = (float*)d_out;
    u16* qf = (u16*)d_ws;                    // [32][1024][256] fp16
    u16* vf = qf + (size_t)BB * NN * CC;     // fragment-major V, 8.4M u16
    u16* whf = vf + (size_t)BB * NN * CC;    // fragment-major W, 64K u16
    k_wprep<<<32, 256, 0, stream>>>(w, whf);
    k_split<<<2048, 256, 0, stream>>>(x, qf);
    k_vgemm<<<512, 256, 0, stream>>>(qf, whf, bias, vf);
    k_attn<<<512, 256, 0, stream>>>(qf, vf, out);
}